// Round 1
// baseline (286.205 us; speedup 1.0000x reference)
//
#include <hip/hip_runtime.h>
#include <math.h>

#define DIM_ 512
#define K_ 128
#define EPS_ 1e-6f
#define MARGIN_ 2.0f

__device__ __forceinline__ float wsum(float v) {
#pragma unroll
    for (int off = 32; off >= 1; off >>= 1)
        v += __shfl_xor(v, off, 64);
    return v;
}

__device__ __forceinline__ void givens_rot(float gc, float gs, float& x0, float& x1) {
    float n = fmaxf(sqrtf(gc * gc + gs * gs), 1e-15f);
    float c = gc / n, s = gs / n;
    float y0 = c * x0 - s * x1;
    float y1 = c * x1 + s * x0;
    x0 = y0; x1 = y1;
}

__device__ __forceinline__ void givens_ref(float gc, float gs, float& x0, float& x1) {
    float n = fmaxf(sqrtf(gc * gc + gs * gs), 1e-15f);
    float c = gc / n, s = gs / n;
    float y0 = c * x0 + s * x1;
    float y1 = s * x0 - c * x1;
    x0 = y0; x1 = y1;
}

// One block = 4 waves, block (b, kchunk). Each wave handles 8 tails.
// Lane l owns head/tail elements [8l, 8l+8): head kept entirely in registers.
__global__ __launch_bounds__(256) void ultrae_kernel(
    const float* __restrict__ emb,        // [N_ENT, 512]
    const float* __restrict__ rel_boost,  // [N_REL, 2]
    const float* __restrict__ rot_left,   // [N_REL, 512]
    const float* __restrict__ rot_right,  // [N_REL, 512]
    const float* __restrict__ bias_head,  // [N_ENT]
    const float* __restrict__ bias_tail,  // [N_ENT]
    const int* __restrict__ u_idx,        // [B]
    const int* __restrict__ r_idx,        // [B]
    const int* __restrict__ v_idx,        // [B, K]
    float* __restrict__ out)              // [B, K]
{
    const int b = blockIdx.x;
    const int lane = threadIdx.x & 63;
    const int wave = threadIdx.x >> 6;
    const int u = u_idx[b];
    const int r = r_idx[b];

    // ---- head: load + expmap0 ----
    const float* hrow = emb + (size_t)u * DIM_ + lane * 8;
    float4 h0 = *(const float4*)hrow;
    float4 h1 = *(const float4*)(hrow + 4);
    if (lane == 0) h0.x = 0.f;              // proj_tan0
    float ps = h0.x*h0.x + h0.y*h0.y + h0.z*h0.z + h0.w*h0.w
             + h1.x*h1.x + h1.y*h1.y + h1.z*h1.z + h1.w*h1.w;
    float tot = wsum(ps);
    float u1 = __shfl(h0.y, 0, 64);
    float a = tot - 2.f * u1 * u1;          // -u1^2 + sum_{i>=2} u_i^2
    float ch, sh;
    if (a > 0.f) {
        float sp = sqrtf(fmaxf(a, EPS_));
        ch = coshf(sp); sh = sinhf(sp) / sp;
    } else {
        float st = sqrtf(fmaxf(-a, EPS_));
        ch = cosf(st); sh = sinf(st) / st;
    }
    h0.x *= sh; h0.y *= sh; h0.z *= sh; h0.w *= sh;
    h1.x *= sh; h1.y *= sh; h1.z *= sh; h1.w *= sh;
    if (lane == 0) h0.x = ch;               // out[0] = c

    // ---- givens rotation with rot_right ----
    const float* rr = rot_right + (size_t)r * DIM_ + lane * 8;
    float4 g0 = *(const float4*)rr;
    float4 g1 = *(const float4*)(rr + 4);
    givens_rot(g0.x, g0.y, h0.x, h0.y);
    givens_rot(g0.z, g0.w, h0.z, h0.w);
    givens_rot(g1.x, g1.y, h1.x, h1.y);
    givens_rot(g1.z, g1.w, h1.z, h1.w);

    // ---- boost: mixes dims {0,510} and {1,511} ----
    float bb0 = log1pf(expf(rel_boost[2*r]));
    float bb1 = log1pf(expf(rel_boost[2*r+1]));
    float C0 = sqrtf(1.f + bb0*bb0);
    float C1 = sqrtf(1.f + bb1*bb1);
    float e0   = __shfl(h0.x, 0, 64);
    float e1   = __shfl(h0.y, 0, 64);
    float e510 = __shfl(h1.z, 63, 64);
    float e511 = __shfl(h1.w, 63, 64);
    if (lane == 0) {
        h0.x = C0*e0 - bb0*e510;
        h0.y = C1*e1 - bb1*e511;
    }
    if (lane == 63) {
        h1.z = C0*e510 - bb0*e0;
        h1.w = C1*e511 - bb1*e1;
    }

    // ---- givens reflection with rot_left ----
    const float* rl = rot_left + (size_t)r * DIM_ + lane * 8;
    g0 = *(const float4*)rl;
    g1 = *(const float4*)(rl + 4);
    givens_ref(g0.x, g0.y, h0.x, h0.y);
    givens_ref(g0.z, g0.w, h0.z, h0.w);
    givens_ref(g1.x, g1.y, h1.x, h1.y);
    givens_ref(g1.z, g1.w, h1.z, h1.w);

    // ---- head scalars ----
    float hf0 = __shfl(h0.x, 0, 64);
    float hf1 = __shfl(h0.y, 0, 64);
    float nx = sqrtf(hf0*hf0 + hf1*hf1);
    if (lane == 0) { h0.x = 0.f; h0.y = 0.f; }   // spatial dot excludes dims 0,1
    float bh = bias_head[u];

    // ---- inner loop over 8 tails ----
    const int kbase = (blockIdx.y * 4 + wave) * 8;
    const int* vp = v_idx + b * K_ + kbase;

#pragma unroll
    for (int i = 0; i < 8; ++i) {
        int v = vp[i];
        const float* trow = emb + (size_t)v * DIM_ + lane * 8;
        float4 t0 = *(const float4*)trow;
        float4 t1 = *(const float4*)(trow + 4);
        float tt1 = __shfl(t0.y, 0, 64);
        if (lane == 0) { t0.x = 0.f; t0.y = 0.f; }
        float q = t0.x*t0.x + t0.y*t0.y + t0.z*t0.z + t0.w*t0.w
                + t1.x*t1.x + t1.y*t1.y + t1.z*t1.z + t1.w*t1.w;
        float d = h0.x*t0.x + h0.y*t0.y + h0.z*t0.z + h0.w*t0.w
                + h1.x*t1.x + h1.y*t1.y + h1.z*t1.z + h1.w*t1.w;
#pragma unroll
        for (int off = 32; off >= 1; off >>= 1) {
            q += __shfl_xor(q, off, 64);
            d += __shfl_xor(d, off, 64);
        }
        float at = q - tt1 * tt1;           // -t1^2 + sum_{i>=2} t_i^2
        float ct, st;
        if (at > 0.f) {
            float sp = sqrtf(fmaxf(at, EPS_));
            ct = coshf(sp); st = sinhf(sp) / sp;
        } else {
            float s2 = sqrtf(fmaxf(-at, EPS_));
            ct = cosf(s2); st = sinf(s2) / s2;
        }
        float yt1 = st * tt1;               // transformed tail time[1]; time[0]=ct
        float ny = sqrtf(ct*ct + yt1*yt1);
        float dott = hf0*ct + hf1*yt1;
        float cosang = dott / (nx * ny);
        cosang = fminf(fmaxf(cosang, -1.f + EPS_), 1.f - EPS_);
        float ang = acosf(cosang);
        float dsph = fminf(nx, ny) * ang;   // min(c1,c2) folds here
        float inner = fmaxf(nx*ny - st*d, 1.f + EPS_);
        float dhyp = acoshf(inner);
        float dsum = dsph + dhyp;
        if (lane == 0) {
            out[b * K_ + kbase + i] = MARGIN_ - dsum*dsum + bh + bias_tail[v];
        }
    }
}

extern "C" void kernel_launch(void* const* d_in, const int* in_sizes, int n_in,
                              void* d_out, int out_size, void* d_ws, size_t ws_size,
                              hipStream_t stream) {
    const float* emb       = (const float*)d_in[0];
    const float* rel_boost = (const float*)d_in[1];
    const float* rot_left  = (const float*)d_in[2];
    const float* rot_right = (const float*)d_in[3];
    const float* bias_h    = (const float*)d_in[4];
    const float* bias_t    = (const float*)d_in[5];
    const int* u_idx       = (const int*)d_in[6];
    const int* r_idx       = (const int*)d_in[7];
    const int* v_idx       = (const int*)d_in[8];
    float* out = (float*)d_out;

    int B = in_sizes[6];           // 512
    dim3 grid(B, 4), block(256);
    hipLaunchKernelGGL(ultrae_kernel, grid, block, 0, stream,
                       emb, rel_boost, rot_left, rot_right,
                       bias_h, bias_t, u_idx, r_idx, v_idx, out);
}

// Round 3
// 279.397 us; speedup vs baseline: 1.0244x; 1.0244x over previous
//
#include <hip/hip_runtime.h>
#include <math.h>

#define DIM_ 512
#define K_ 128
#define EPS_ 1e-6f
#define MARGIN_ 2.0f
#define PI_ 3.14159265358979f

__device__ __forceinline__ float frcp(float x) { return __builtin_amdgcn_rcpf(x); }

// Abramowitz-Stegun 4.4.45: |err| <= 6.7e-5 on [-1,1]
__device__ __forceinline__ float fast_acos(float x) {
    float ax = fabsf(x);
    float p = -0.0187293f;
    p = p * ax + 0.0742610f;
    p = p * ax - 0.2121144f;
    p = p * ax + 1.5707288f;
    float r = sqrtf(fmaxf(1.f - ax, 0.f)) * p;
    return x < 0.f ? PI_ - r : r;
}

__device__ __forceinline__ void fast_coshsinh(float x, float& c, float& s) {
    float e  = __expf(x);           // v_exp_f32 path; x <= ~25 here, no overflow
    float ei = frcp(e);
    c = 0.5f * (e + ei);
    s = 0.5f * (e - ei);
}

// expmap0 scalars from a = -t1^2 + sum_{i>=2} u_i^2 (u[0] forced 0)
__device__ __forceinline__ void expmap_cs(float a, float& c, float& s) {
    if (a > 0.f) {
        float sp = sqrtf(fmaxf(a, EPS_));
        float ch, sh;
        fast_coshsinh(sp, ch, sh);
        c = ch; s = sh * frcp(sp);
    } else {
        float st = sqrtf(fmaxf(-a, EPS_));
        c = __cosf(st);
        s = __sinf(st) * frcp(st);
    }
}

__device__ __forceinline__ void givens_rot(float gc, float gs, float& x0, float& x1) {
    float rn = frcp(fmaxf(sqrtf(gc * gc + gs * gs), 1e-15f));
    float c = gc * rn, s = gs * rn;
    float y0 = c * x0 - s * x1;
    float y1 = c * x1 + s * x0;
    x0 = y0; x1 = y1;
}

__device__ __forceinline__ void givens_ref(float gc, float gs, float& x0, float& x1) {
    float rn = frcp(fmaxf(sqrtf(gc * gc + gs * gs), 1e-15f));
    float c = gc * rn, s = gs * rn;
    float y0 = c * x0 + s * x1;
    float y1 = s * x0 - c * x1;
    x0 = y0; x1 = y1;
}

// grid (B, 8) x 256 threads: 4 waves/block, 4 tails/wave -> 8*4*4 = 128 tails per b.
// Lane l owns elements [8l, 8l+8) of every 512-dim row; head lives in 8 regs/lane.
__global__ __launch_bounds__(256) void ultrae_kernel(
    const float* __restrict__ emb,        // [N_ENT, 512]
    const float* __restrict__ rel_boost,  // [N_REL, 2]
    const float* __restrict__ rot_left,   // [N_REL, 512]
    const float* __restrict__ rot_right,  // [N_REL, 512]
    const float* __restrict__ bias_head,  // [N_ENT]
    const float* __restrict__ bias_tail,  // [N_ENT]
    const int* __restrict__ u_idx,        // [B]
    const int* __restrict__ r_idx,        // [B]
    const int* __restrict__ v_idx,        // [B, K]
    float* __restrict__ out)              // [B, K]
{
    const int b = blockIdx.x;
    const int lane = threadIdx.x & 63;
    const int wave = threadIdx.x >> 6;
    const int u = u_idx[b];
    const int r = r_idx[b];

    // ---- issue tail index + row loads as early as possible (MLP) ----
    const int kbase = (blockIdx.y * 4 + wave) * 4;
    const int4 vv = *(const int4*)(v_idx + b * K_ + kbase);
    const int vi[4] = {vv.x, vv.y, vv.z, vv.w};
    float4 t0[4], t1[4];
#pragma unroll
    for (int i = 0; i < 4; ++i) {
        const float* trow = emb + (size_t)vi[i] * DIM_ + lane * 8;
        t0[i] = *(const float4*)trow;
        t1[i] = *(const float4*)(trow + 4);
    }

    // ---- head: load + expmap0 ----
    const float* hrow = emb + (size_t)u * DIM_ + lane * 8;
    float4 h0 = *(const float4*)hrow;
    float4 h1 = *(const float4*)(hrow + 4);
    if (lane == 0) h0.x = 0.f;              // proj_tan0
    float ps = h0.x*h0.x + h0.y*h0.y + h0.z*h0.z + h0.w*h0.w
             + h1.x*h1.x + h1.y*h1.y + h1.z*h1.z + h1.w*h1.w;
#pragma unroll
    for (int off = 32; off >= 1; off >>= 1) ps += __shfl_xor(ps, off, 64);
    float u1 = __shfl(h0.y, 0, 64);
    float a = ps - 2.f * u1 * u1;           // -u1^2 + sum_{i>=2} u_i^2
    float ch, sh;
    expmap_cs(a, ch, sh);
    h0.x *= sh; h0.y *= sh; h0.z *= sh; h0.w *= sh;
    h1.x *= sh; h1.y *= sh; h1.z *= sh; h1.w *= sh;
    if (lane == 0) h0.x = ch;               // out[0] = c

    // ---- givens rotation (rot_right) ----
    {
        const float* rr = rot_right + (size_t)r * DIM_ + lane * 8;
        float4 g0 = *(const float4*)rr;
        float4 g1 = *(const float4*)(rr + 4);
        givens_rot(g0.x, g0.y, h0.x, h0.y);
        givens_rot(g0.z, g0.w, h0.z, h0.w);
        givens_rot(g1.x, g1.y, h1.x, h1.y);
        givens_rot(g1.z, g1.w, h1.z, h1.w);
    }

    // ---- boost: mixes dims {0,510} and {1,511} ----
    {
        float bb0 = __logf(1.f + __expf(rel_boost[2*r]));
        float bb1 = __logf(1.f + __expf(rel_boost[2*r+1]));
        float C0 = sqrtf(1.f + bb0*bb0);
        float C1 = sqrtf(1.f + bb1*bb1);
        float e0   = __shfl(h0.x, 0, 64);
        float e1   = __shfl(h0.y, 0, 64);
        float e510 = __shfl(h1.z, 63, 64);
        float e511 = __shfl(h1.w, 63, 64);
        if (lane == 0) {
            h0.x = C0*e0 - bb0*e510;
            h0.y = C1*e1 - bb1*e511;
        }
        if (lane == 63) {
            h1.z = C0*e510 - bb0*e0;
            h1.w = C1*e511 - bb1*e1;
        }
    }

    // ---- givens reflection (rot_left) ----
    {
        const float* rl = rot_left + (size_t)r * DIM_ + lane * 8;
        float4 g0 = *(const float4*)rl;
        float4 g1 = *(const float4*)(rl + 4);
        givens_ref(g0.x, g0.y, h0.x, h0.y);
        givens_ref(g0.z, g0.w, h0.z, h0.w);
        givens_ref(g1.x, g1.y, h1.x, h1.y);
        givens_ref(g1.z, g1.w, h1.z, h1.w);
    }

    // ---- head scalars ----
    float hf0 = __shfl(h0.x, 0, 64);
    float hf1 = __shfl(h0.y, 0, 64);
    float nx = sqrtf(hf0*hf0 + hf1*hf1);
    if (lane == 0) { h0.x = 0.f; h0.y = 0.f; }   // spatial dot excludes dims 0,1
    const float bh = bias_head[u];
    const float rnx = frcp(nx);

    // ---- 4 tails per wave ----
#pragma unroll
    for (int i = 0; i < 4; ++i) {
        float4 s0 = t0[i], s1 = t1[i];
        float tt1 = __shfl(s0.y, 0, 64);
        if (lane == 0) { s0.x = 0.f; s0.y = 0.f; }
        float q = s0.x*s0.x + s0.y*s0.y + s0.z*s0.z + s0.w*s0.w
                + s1.x*s1.x + s1.y*s1.y + s1.z*s1.z + s1.w*s1.w;
        float d = h0.x*s0.x + h0.y*s0.y + h0.z*s0.z + h0.w*s0.w
                + h1.x*s1.x + h1.y*s1.y + h1.z*s1.z + h1.w*s1.w;
#pragma unroll
        for (int off = 32; off >= 1; off >>= 1) {
            q += __shfl_xor(q, off, 64);
            d += __shfl_xor(d, off, 64);
        }
        float at = q - tt1 * tt1;           // -t1^2 + sum_{i>=2} t_i^2
        float ct, st;
        expmap_cs(at, ct, st);
        float yt1 = st * tt1;               // tail time = (ct, st*t1)
        float ny = sqrtf(ct*ct + yt1*yt1);
        float cosang = (hf0*ct + hf1*yt1) * rnx * frcp(ny);
        cosang = fminf(fmaxf(cosang, -1.f + EPS_), 1.f - EPS_);
        float dsph = fminf(nx, ny) * fast_acos(cosang);   // min(c1,c2) folds here
        float inner = fmaxf(nx*ny - st*d, 1.f + EPS_);
        // acosh(x) = log(x + sqrt(x-1)*sqrt(x+1)) — factored sqrts avoid x^2
        // overflow (inner reaches ~2e19; inner^2 would exceed f32 max -> inf)
        float dhyp = __logf(inner + sqrtf(inner - 1.f) * sqrtf(inner + 1.f));
        float dsum = dsph + dhyp;
        if (lane == 0) {
            out[b * K_ + kbase + i] = MARGIN_ - dsum*dsum + bh + bias_tail[vi[i]];
        }
    }
}

extern "C" void kernel_launch(void* const* d_in, const int* in_sizes, int n_in,
                              void* d_out, int out_size, void* d_ws, size_t ws_size,
                              hipStream_t stream) {
    const float* emb       = (const float*)d_in[0];
    const float* rel_boost = (const float*)d_in[1];
    const float* rot_left  = (const float*)d_in[2];
    const float* rot_right = (const float*)d_in[3];
    const float* bias_h    = (const float*)d_in[4];
    const float* bias_t    = (const float*)d_in[5];
    const int* u_idx       = (const int*)d_in[6];
    const int* r_idx       = (const int*)d_in[7];
    const int* v_idx       = (const int*)d_in[8];
    float* out = (float*)d_out;

    int B = in_sizes[6];           // 512
    dim3 grid(B, 8), block(256);
    hipLaunchKernelGGL(ultrae_kernel, grid, block, 0, stream,
                       emb, rel_boost, rot_left, rot_right,
                       bias_h, bias_t, u_idx, r_idx, v_idx, out);
}

// Round 4
// 273.386 us; speedup vs baseline: 1.0469x; 1.0220x over previous
//
#include <hip/hip_runtime.h>
#include <math.h>

#define DIM_ 512
#define K_ 128
#define EPS_ 1e-6f
#define MARGIN_ 2.0f
#define PI_ 3.14159265358979f
#define QSTRIDE 68   // floats between consecutive tails' partial rows; 68%32=4 -> <=2-way bank aliasing (free)

__device__ __forceinline__ float frcp(float x) { return __builtin_amdgcn_rcpf(x); }

// Abramowitz-Stegun 4.4.45: |err| <= 6.7e-5 on [-1,1]
__device__ __forceinline__ float fast_acos(float x) {
    float ax = fabsf(x);
    float p = -0.0187293f;
    p = p * ax + 0.0742610f;
    p = p * ax - 0.2121144f;
    p = p * ax + 1.5707288f;
    float r = sqrtf(fmaxf(1.f - ax, 0.f)) * p;
    return x < 0.f ? PI_ - r : r;
}

__device__ __forceinline__ void fast_coshsinh(float x, float& c, float& s) {
    float e  = __expf(x);           // x <= ~25 here, no overflow
    float ei = frcp(e);
    c = 0.5f * (e + ei);
    s = 0.5f * (e - ei);
}

// expmap0 scalars from a = -t1^2 + sum_{i>=2} u_i^2 (u[0] forced 0)
__device__ __forceinline__ void expmap_cs(float a, float& c, float& s) {
    if (a > 0.f) {
        float sp = sqrtf(fmaxf(a, EPS_));
        float ch, sh;
        fast_coshsinh(sp, ch, sh);
        c = ch; s = sh * frcp(sp);
    } else {
        float st = sqrtf(fmaxf(-a, EPS_));
        c = __cosf(st);
        s = __sinf(st) * frcp(st);
    }
}

__device__ __forceinline__ void givens_rot(float gc, float gs, float& x0, float& x1) {
    float rn = frcp(fmaxf(sqrtf(gc * gc + gs * gs), 1e-15f));
    float c = gc * rn, s = gs * rn;
    float y0 = c * x0 - s * x1;
    float y1 = c * x1 + s * x0;
    x0 = y0; x1 = y1;
}

__device__ __forceinline__ void givens_ref(float gc, float gs, float& x0, float& x1) {
    float rn = frcp(fmaxf(sqrtf(gc * gc + gs * gs), 1e-15f));
    float c = gc * rn, s = gs * rn;
    float y0 = c * x0 + s * x1;
    float y1 = s * x0 - c * x1;
    x0 = y0; x1 = y1;
}

// grid (B, 4) x 256 threads: 4 waves/block, 8 tails/wave -> 4*4*8 = 128 tails per b.
// Lane l owns elements [8l, 8l+8) of every 512-dim row. Per-tail scalar math is
// computed 8-way lane-parallel after an LDS transpose of the (q,d) partials.
__global__ __launch_bounds__(256) void ultrae_kernel(
    const float* __restrict__ emb,        // [N_ENT, 512]
    const float* __restrict__ rel_boost,  // [N_REL, 2]
    const float* __restrict__ rot_left,   // [N_REL, 512]
    const float* __restrict__ rot_right,  // [N_REL, 512]
    const float* __restrict__ bias_head,  // [N_ENT]
    const float* __restrict__ bias_tail,  // [N_ENT]
    const int* __restrict__ u_idx,        // [B]
    const int* __restrict__ r_idx,        // [B]
    const int* __restrict__ v_idx,        // [B, K]
    float* __restrict__ out)              // [B, K]
{
    __shared__ float lds_q[4][8 * QSTRIDE + 4];
    __shared__ float lds_d[4][8 * QSTRIDE + 4];

    const int b = blockIdx.x;
    const int lane = threadIdx.x & 63;
    const int wave = threadIdx.x >> 6;
    const int u = u_idx[b];
    const int r = r_idx[b];

    // ---- issue tail index + row loads as early as possible (MLP) ----
    const int kbase = (blockIdx.y * 4 + wave) * 8;
    const int* vp = v_idx + b * K_ + kbase;
    const int4 vv0 = *(const int4*)(vp);
    const int4 vv1 = *(const int4*)(vp + 4);
    const int vi[8] = {vv0.x, vv0.y, vv0.z, vv0.w, vv1.x, vv1.y, vv1.z, vv1.w};
    float4 t0[8], t1[8];
#pragma unroll
    for (int j = 0; j < 8; ++j) {
        const float* trow = emb + (size_t)vi[j] * DIM_ + lane * 8;
        t0[j] = *(const float4*)trow;
        t1[j] = *(const float4*)(trow + 4);
    }

    // per-lane tail (for the lane-parallel scalar phase): lane handles tail m = lane&7
    const int m = lane & 7;
    const int g = lane >> 3;
    const int vm = vp[m];
    const float tt1 = emb[(size_t)vm * DIM_ + 1];   // raw tail element 1 (row is L1/L2-hot)
    const float bt = bias_tail[vm];

    // ---- head: load + expmap0 ----
    const float* hrow = emb + (size_t)u * DIM_ + lane * 8;
    float4 h0 = *(const float4*)hrow;
    float4 h1 = *(const float4*)(hrow + 4);
    if (lane == 0) h0.x = 0.f;              // proj_tan0
    float ps = h0.x*h0.x + h0.y*h0.y + h0.z*h0.z + h0.w*h0.w
             + h1.x*h1.x + h1.y*h1.y + h1.z*h1.z + h1.w*h1.w;
#pragma unroll
    for (int off = 32; off >= 1; off >>= 1) ps += __shfl_xor(ps, off, 64);
    float u1 = __shfl(h0.y, 0, 64);
    float a = ps - 2.f * u1 * u1;           // -u1^2 + sum_{i>=2} u_i^2
    float ch, sh;
    expmap_cs(a, ch, sh);
    h0.x *= sh; h0.y *= sh; h0.z *= sh; h0.w *= sh;
    h1.x *= sh; h1.y *= sh; h1.z *= sh; h1.w *= sh;
    if (lane == 0) h0.x = ch;               // out[0] = c

    // ---- givens rotation (rot_right) ----
    {
        const float* rr = rot_right + (size_t)r * DIM_ + lane * 8;
        float4 g0 = *(const float4*)rr;
        float4 g1 = *(const float4*)(rr + 4);
        givens_rot(g0.x, g0.y, h0.x, h0.y);
        givens_rot(g0.z, g0.w, h0.z, h0.w);
        givens_rot(g1.x, g1.y, h1.x, h1.y);
        givens_rot(g1.z, g1.w, h1.z, h1.w);
    }

    // ---- boost: mixes dims {0,510} and {1,511} ----
    {
        float bb0 = __logf(1.f + __expf(rel_boost[2*r]));
        float bb1 = __logf(1.f + __expf(rel_boost[2*r+1]));
        float C0 = sqrtf(1.f + bb0*bb0);
        float C1 = sqrtf(1.f + bb1*bb1);
        float e0   = __shfl(h0.x, 0, 64);
        float e1   = __shfl(h0.y, 0, 64);
        float e510 = __shfl(h1.z, 63, 64);
        float e511 = __shfl(h1.w, 63, 64);
        if (lane == 0) {
            h0.x = C0*e0 - bb0*e510;
            h0.y = C1*e1 - bb1*e511;
        }
        if (lane == 63) {
            h1.z = C0*e510 - bb0*e0;
            h1.w = C1*e511 - bb1*e1;
        }
    }

    // ---- givens reflection (rot_left) ----
    {
        const float* rl = rot_left + (size_t)r * DIM_ + lane * 8;
        float4 g0 = *(const float4*)rl;
        float4 g1 = *(const float4*)(rl + 4);
        givens_ref(g0.x, g0.y, h0.x, h0.y);
        givens_ref(g0.z, g0.w, h0.z, h0.w);
        givens_ref(g1.x, g1.y, h1.x, h1.y);
        givens_ref(g1.z, g1.w, h1.z, h1.w);
    }

    // ---- head scalars ----
    float hf0 = __shfl(h0.x, 0, 64);
    float hf1 = __shfl(h0.y, 0, 64);
    float nx = sqrtf(hf0*hf0 + hf1*hf1);
    if (lane == 0) { h0.x = 0.f; h0.y = 0.f; }   // spatial dot excludes dims 0,1
    const float bh = bias_head[u];
    const float rnx = frcp(nx);

    // ---- per-lane (q,d) partials for all 8 tails -> LDS ----
#pragma unroll
    for (int j = 0; j < 8; ++j) {
        float4 s0 = t0[j], s1 = t1[j];
        if (lane == 0) { s0.x = 0.f; s0.y = 0.f; }
        float qp = s0.x*s0.x + s0.y*s0.y + s0.z*s0.z + s0.w*s0.w
                 + s1.x*s1.x + s1.y*s1.y + s1.z*s1.z + s1.w*s1.w;
        float dp = h0.x*s0.x + h0.y*s0.y + h0.z*s0.z + h0.w*s0.w
                 + h1.x*s1.x + h1.y*s1.y + h1.z*s1.z + h1.w*s1.w;
        lds_q[wave][j * QSTRIDE + lane] = qp;
        lds_d[wave][j * QSTRIDE + lane] = dp;
    }

    // DS ops within a wave execute in order; barrier only pins compiler scheduling.
    __builtin_amdgcn_wave_barrier();

    // ---- transposed accumulate: lane (m,g) sums partials p = g+8k of tail m ----
    float q = 0.f, d = 0.f;
    const float* qa = &lds_q[wave][m * QSTRIDE + g];
    const float* da = &lds_d[wave][m * QSTRIDE + g];
#pragma unroll
    for (int k = 0; k < 8; ++k) {
        q += qa[8 * k];
        d += da[8 * k];
    }
    // finish across the g dimension (lanes differing in bits 3..5)
    q += __shfl_xor(q, 8, 64);  d += __shfl_xor(d, 8, 64);
    q += __shfl_xor(q, 16, 64); d += __shfl_xor(d, 16, 64);
    q += __shfl_xor(q, 32, 64); d += __shfl_xor(d, 32, 64);

    // ---- per-tail scalar math, 8-way lane-parallel (tail m per lane) ----
    float at = q - tt1 * tt1;               // -t1^2 + sum_{i>=2} t_i^2
    float ct, st;
    expmap_cs(at, ct, st);
    float yt1 = st * tt1;                   // tail time = (ct, st*t1)
    float ny = sqrtf(ct*ct + yt1*yt1);
    float cosang = (hf0*ct + hf1*yt1) * rnx * frcp(ny);
    cosang = fminf(fmaxf(cosang, -1.f + EPS_), 1.f - EPS_);
    float dsph = fminf(nx, ny) * fast_acos(cosang);   // min(c1,c2) folds here
    float inner = fmaxf(nx*ny - st*d, 1.f + EPS_);
    // acosh(x) = log(x + sqrt(x-1)*sqrt(x+1)) — factored sqrts avoid x^2 overflow
    float dhyp = __logf(inner + sqrtf(inner - 1.f) * sqrtf(inner + 1.f));
    float dsum = dsph + dhyp;
    if (lane < 8) {
        out[b * K_ + kbase + m] = MARGIN_ - dsum*dsum + bh + bt;
    }
}

extern "C" void kernel_launch(void* const* d_in, const int* in_sizes, int n_in,
                              void* d_out, int out_size, void* d_ws, size_t ws_size,
                              hipStream_t stream) {
    const float* emb       = (const float*)d_in[0];
    const float* rel_boost = (const float*)d_in[1];
    const float* rot_left  = (const float*)d_in[2];
    const float* rot_right = (const float*)d_in[3];
    const float* bias_h    = (const float*)d_in[4];
    const float* bias_t    = (const float*)d_in[5];
    const int* u_idx       = (const int*)d_in[6];
    const int* r_idx       = (const int*)d_in[7];
    const int* v_idx       = (const int*)d_in[8];
    float* out = (float*)d_out;

    int B = in_sizes[6];           // 512
    dim3 grid(B, 4), block(256);
    hipLaunchKernelGGL(ultrae_kernel, grid, block, 0, stream,
                       emb, rel_boost, rot_left, rot_right,
                       bias_h, bias_t, u_idx, r_idx, v_idx, out);
}

// Round 5
// 273.009 us; speedup vs baseline: 1.0483x; 1.0014x over previous
//
#include <hip/hip_runtime.h>
#include <math.h>

#define DIM_ 512
#define K_ 128
#define EPS_ 1e-6f
#define MARGIN_ 2.0f
#define PI_ 3.14159265358979f
#define QSTRIDE 68   // floats between consecutive tails' partial rows; 68%32=4 -> <=2-way bank aliasing (free)

__device__ __forceinline__ float frcp(float x) { return __builtin_amdgcn_rcpf(x); }

// Abramowitz-Stegun 4.4.45: |err| <= 6.7e-5 on [-1,1]
__device__ __forceinline__ float fast_acos(float x) {
    float ax = fabsf(x);
    float p = -0.0187293f;
    p = p * ax + 0.0742610f;
    p = p * ax - 0.2121144f;
    p = p * ax + 1.5707288f;
    float r = sqrtf(fmaxf(1.f - ax, 0.f)) * p;
    return x < 0.f ? PI_ - r : r;
}

__device__ __forceinline__ void fast_coshsinh(float x, float& c, float& s) {
    float e  = __expf(x);           // x <= ~25 here, no overflow
    float ei = frcp(e);
    c = 0.5f * (e + ei);
    s = 0.5f * (e - ei);
}

// expmap0 scalars from a = -t1^2 + sum_{i>=2} u_i^2 (u[0] forced 0)
__device__ __forceinline__ void expmap_cs(float a, float& c, float& s) {
    if (a > 0.f) {
        float sp = sqrtf(fmaxf(a, EPS_));
        float ch, sh;
        fast_coshsinh(sp, ch, sh);
        c = ch; s = sh * frcp(sp);
    } else {
        float st = sqrtf(fmaxf(-a, EPS_));
        c = __cosf(st);
        s = __sinf(st) * frcp(st);
    }
}

__device__ __forceinline__ void givens_rot(float gc, float gs, float& x0, float& x1) {
    float rn = frcp(fmaxf(sqrtf(gc * gc + gs * gs), 1e-15f));
    float c = gc * rn, s = gs * rn;
    float y0 = c * x0 - s * x1;
    float y1 = c * x1 + s * x0;
    x0 = y0; x1 = y1;
}

__device__ __forceinline__ void givens_ref(float gc, float gs, float& x0, float& x1) {
    float rn = frcp(fmaxf(sqrtf(gc * gc + gs * gs), 1e-15f));
    float c = gc * rn, s = gs * rn;
    float y0 = c * x0 + s * x1;
    float y1 = s * x0 - c * x1;
    x0 = y0; x1 = y1;
}

// grid (B, 4) x 256 threads: 4 waves/block, 8 tails/wave -> 4*4*8 = 128 tails per b.
// Lane l owns elements [8l, 8l+8) of every 512-dim row. Per-tail scalar math is
// computed 8-way lane-parallel after an LDS transpose of the (q,d) partials.
__global__ __launch_bounds__(256) void ultrae_kernel(
    const float* __restrict__ emb,        // [N_ENT, 512]
    const float* __restrict__ rel_boost,  // [N_REL, 2]
    const float* __restrict__ rot_left,   // [N_REL, 512]
    const float* __restrict__ rot_right,  // [N_REL, 512]
    const float* __restrict__ bias_head,  // [N_ENT]
    const float* __restrict__ bias_tail,  // [N_ENT]
    const int* __restrict__ u_idx,        // [B]
    const int* __restrict__ r_idx,        // [B]
    const int* __restrict__ v_idx,        // [B, K]
    float* __restrict__ out)              // [B, K]
{
    __shared__ float lds_q[4][8 * QSTRIDE + 4];
    __shared__ float lds_d[4][8 * QSTRIDE + 4];
    __shared__ float lds_t[4][8];

    const int b = blockIdx.x;
    const int lane = threadIdx.x & 63;
    const int wave = threadIdx.x >> 6;
    const int u = u_idx[b];
    const int r = r_idx[b];

    // ---- issue ALL global loads first (max memory-level parallelism) ----
    const int kbase = (blockIdx.y * 4 + wave) * 8;
    const int* vp = v_idx + b * K_ + kbase;
    const int4 vv0 = *(const int4*)(vp);
    const int4 vv1 = *(const int4*)(vp + 4);
    const int vi[8] = {vv0.x, vv0.y, vv0.z, vv0.w, vv1.x, vv1.y, vv1.z, vv1.w};
    float4 t0[8], t1[8];
#pragma unroll
    for (int j = 0; j < 8; ++j) {
        const float* trow = emb + (size_t)vi[j] * DIM_ + lane * 8;
        t0[j] = *(const float4*)trow;
        t1[j] = *(const float4*)(trow + 4);
    }

    const float* hrow = emb + (size_t)u * DIM_ + lane * 8;
    float4 h0 = *(const float4*)hrow;
    float4 h1 = *(const float4*)(hrow + 4);
    const float* rr = rot_right + (size_t)r * DIM_ + lane * 8;
    float4 gr0 = *(const float4*)rr;
    float4 gr1 = *(const float4*)(rr + 4);
    const float* rl = rot_left + (size_t)r * DIM_ + lane * 8;
    float4 gl0 = *(const float4*)rl;
    float4 gl1 = *(const float4*)(rl + 4);
    const float rb0 = rel_boost[2*r];
    const float rb1 = rel_boost[2*r+1];
    const float bh = bias_head[u];

    // per-lane tail for the lane-parallel scalar phase: lane handles tail m = lane&7
    const int m = lane & 7;
    const int g = lane >> 3;
    float bt = 0.f;
    if (lane < 8) bt = bias_tail[vp[m]];   // only the 8 storing lanes need it

    // ---- head: expmap0 ----
    if (lane == 0) h0.x = 0.f;              // proj_tan0
    float ps = h0.x*h0.x + h0.y*h0.y + h0.z*h0.z + h0.w*h0.w
             + h1.x*h1.x + h1.y*h1.y + h1.z*h1.z + h1.w*h1.w;
#pragma unroll
    for (int off = 32; off >= 1; off >>= 1) ps += __shfl_xor(ps, off, 64);
    float u1 = __shfl(h0.y, 0, 64);
    float a = ps - 2.f * u1 * u1;           // -u1^2 + sum_{i>=2} u_i^2
    float ch, sh;
    expmap_cs(a, ch, sh);
    h0.x *= sh; h0.y *= sh; h0.z *= sh; h0.w *= sh;
    h1.x *= sh; h1.y *= sh; h1.z *= sh; h1.w *= sh;
    if (lane == 0) h0.x = ch;               // out[0] = c

    // ---- givens rotation (rot_right) ----
    givens_rot(gr0.x, gr0.y, h0.x, h0.y);
    givens_rot(gr0.z, gr0.w, h0.z, h0.w);
    givens_rot(gr1.x, gr1.y, h1.x, h1.y);
    givens_rot(gr1.z, gr1.w, h1.z, h1.w);

    // ---- boost: mixes dims {0,510} and {1,511} ----
    {
        float bb0 = __logf(1.f + __expf(rb0));
        float bb1 = __logf(1.f + __expf(rb1));
        float C0 = sqrtf(1.f + bb0*bb0);
        float C1 = sqrtf(1.f + bb1*bb1);
        float e0   = __shfl(h0.x, 0, 64);
        float e1   = __shfl(h0.y, 0, 64);
        float e510 = __shfl(h1.z, 63, 64);
        float e511 = __shfl(h1.w, 63, 64);
        if (lane == 0) {
            h0.x = C0*e0 - bb0*e510;
            h0.y = C1*e1 - bb1*e511;
        }
        if (lane == 63) {
            h1.z = C0*e510 - bb0*e0;
            h1.w = C1*e511 - bb1*e1;
        }
    }

    // ---- givens reflection (rot_left) ----
    givens_ref(gl0.x, gl0.y, h0.x, h0.y);
    givens_ref(gl0.z, gl0.w, h0.z, h0.w);
    givens_ref(gl1.x, gl1.y, h1.x, h1.y);
    givens_ref(gl1.z, gl1.w, h1.z, h1.w);

    // ---- head scalars ----
    float hf0 = __shfl(h0.x, 0, 64);
    float hf1 = __shfl(h0.y, 0, 64);
    float nx = sqrtf(hf0*hf0 + hf1*hf1);
    if (lane == 0) { h0.x = 0.f; h0.y = 0.f; }   // spatial dot excludes dims 0,1
    const float rnx = frcp(nx);

    // ---- stash raw tail element 1 (lives in lane 0's t0[j].y) for scalar phase ----
    if (lane == 0) {
#pragma unroll
        for (int j = 0; j < 8; ++j) lds_t[wave][j] = t0[j].y;
    }

    // ---- per-lane (q,d) partials for all 8 tails -> LDS ----
#pragma unroll
    for (int j = 0; j < 8; ++j) {
        float4 s0 = t0[j], s1 = t1[j];
        if (lane == 0) { s0.x = 0.f; s0.y = 0.f; }
        float qp = s0.x*s0.x + s0.y*s0.y + s0.z*s0.z + s0.w*s0.w
                 + s1.x*s1.x + s1.y*s1.y + s1.z*s1.z + s1.w*s1.w;
        float dp = h0.x*s0.x + h0.y*s0.y + h0.z*s0.z + h0.w*s0.w
                 + h1.x*s1.x + h1.y*s1.y + h1.z*s1.z + h1.w*s1.w;
        lds_q[wave][j * QSTRIDE + lane] = qp;
        lds_d[wave][j * QSTRIDE + lane] = dp;
    }

    // DS ops within a wave execute in order; barrier only pins compiler scheduling.
    __builtin_amdgcn_wave_barrier();

    // ---- transposed accumulate: lane (m,g) sums partials p = g+8k of tail m ----
    float q = 0.f, d = 0.f;
    const float* qa = &lds_q[wave][m * QSTRIDE + g];
    const float* da = &lds_d[wave][m * QSTRIDE + g];
#pragma unroll
    for (int k = 0; k < 8; ++k) {
        q += qa[8 * k];
        d += da[8 * k];
    }
    // finish across the g dimension (lanes differing in bits 3..5)
    q += __shfl_xor(q, 8, 64);  d += __shfl_xor(d, 8, 64);
    q += __shfl_xor(q, 16, 64); d += __shfl_xor(d, 16, 64);
    q += __shfl_xor(q, 32, 64); d += __shfl_xor(d, 32, 64);

    const float tt1 = lds_t[wave][m];       // broadcast read, conflict-free

    // ---- per-tail scalar math, 8-way lane-parallel (tail m per lane) ----
    float at = q - tt1 * tt1;               // -t1^2 + sum_{i>=2} t_i^2
    float ct, st;
    expmap_cs(at, ct, st);
    float yt1 = st * tt1;                   // tail time = (ct, st*t1)
    float ny = sqrtf(ct*ct + yt1*yt1);
    float cosang = (hf0*ct + hf1*yt1) * rnx * frcp(ny);
    cosang = fminf(fmaxf(cosang, -1.f + EPS_), 1.f - EPS_);
    float dsph = fminf(nx, ny) * fast_acos(cosang);   // min(c1,c2) folds here
    float inner = fmaxf(nx*ny - st*d, 1.f + EPS_);
    // acosh(x) = log(x + sqrt(x-1)*sqrt(x+1)) — factored sqrts avoid x^2 overflow
    float dhyp = __logf(inner + sqrtf(inner - 1.f) * sqrtf(inner + 1.f));
    float dsum = dsph + dhyp;
    if (lane < 8) {
        out[b * K_ + kbase + m] = MARGIN_ - dsum*dsum + bh + bt;
    }
}

extern "C" void kernel_launch(void* const* d_in, const int* in_sizes, int n_in,
                              void* d_out, int out_size, void* d_ws, size_t ws_size,
                              hipStream_t stream) {
    const float* emb       = (const float*)d_in[0];
    const float* rel_boost = (const float*)d_in[1];
    const float* rot_left  = (const float*)d_in[2];
    const float* rot_right = (const float*)d_in[3];
    const float* bias_h    = (const float*)d_in[4];
    const float* bias_t    = (const float*)d_in[5];
    const int* u_idx       = (const int*)d_in[6];
    const int* r_idx       = (const int*)d_in[7];
    const int* v_idx       = (const int*)d_in[8];
    float* out = (float*)d_out;

    int B = in_sizes[6];           // 512
    dim3 grid(B, 4), block(256);
    hipLaunchKernelGGL(ultrae_kernel, grid, block, 0, stream,
                       emb, rel_boost, rot_left, rot_right,
                       bias_h, bias_t, u_idx, r_idx, v_idx, out);
}